// Round 4
// baseline (68.844 us; speedup 1.0000x reference)
//
#include <hip/hip_runtime.h>

#define NVELL 1024

typedef float v2 __attribute__((ext_vector_type(2)));

__device__ __forceinline__ float rcp1(float x){ return __builtin_amdgcn_rcpf(x); }
__device__ __forceinline__ v2 bc(float x){ v2 r = {x, x}; return r; }
__device__ __forceinline__ v2 rcp2(v2 x){ v2 r = {rcp1(x.x), rcp1(x.y)}; return r; }
__device__ __forceinline__ v2 exp2v(v2 x){ v2 r = {exp2f(x.x), exp2f(x.y)}; return r; }
__device__ __forceinline__ v2 shf(v2 x, int src){
  v2 r = {__shfl(x.x, src, 64), __shfl(x.y, src, 64)}; return r;
}

__device__ __forceinline__ void wred3v(v2 &a, v2 &b, v2 &c) {
  #pragma unroll
  for (int off = 1; off < 64; off <<= 1) {
    a.x += __shfl_xor(a.x, off, 64); a.y += __shfl_xor(a.y, off, 64);
    b.x += __shfl_xor(b.x, off, 64); b.y += __shfl_xor(b.y, off, 64);
    c.x += __shfl_xor(c.x, off, 64); c.y += __shfl_xor(c.y, off, 64);
  }
}
__device__ __forceinline__ void wred2v(v2 &a, v2 &b) {
  #pragma unroll
  for (int off = 1; off < 64; off <<= 1) {
    a.x += __shfl_xor(a.x, off, 64); a.y += __shfl_xor(a.y, off, 64);
    b.x += __shfl_xor(b.x, off, 64); b.y += __shfl_xor(b.y, off, 64);
  }
}

__global__ __launch_bounds__(256, 4) void fp_step_kernel(
    const float* __restrict__ f, const float* __restrict__ v,
    const float* __restrict__ ve, const float* __restrict__ p_dv,
    const float* __restrict__ p_nu, const float* __restrict__ p_dt,
    float* __restrict__ out, int nrows)
{
  const int lane = threadIdx.x & 63;
  const int wid  = threadIdx.x >> 6;
  const int row0 = blockIdx.x * 8 + wid * 2;
  if (row0 >= nrows) return;
  const int row1 = (row0 + 1 < nrows) ? (row0 + 1) : row0;

  const float dv   = *p_dv;
  const float nu   = *p_nu;
  const float dt   = *p_dt;
  const float vmin = ve[0];
  const int   j0   = lane * 16;

  // ---- load f for both rows (16 contiguous elements per lane, packed) ----
  const float* f0p = f + (size_t)row0 * NVELL + j0;
  const float* f1p = f + (size_t)row1 * NVELL + j0;
  v2 fr[16];
  #pragma unroll
  for (int k = 0; k < 4; ++k) {
    float4 a = reinterpret_cast<const float4*>(f0p)[k];
    float4 b = reinterpret_cast<const float4*>(f1p)[k];
    fr[4*k+0] = (v2){a.x, b.x};
    fr[4*k+1] = (v2){a.y, b.y};
    fr[4*k+2] = (v2){a.z, b.z};
    fr[4*k+3] = (v2){a.w, b.w};
  }

  // cell centers: v_j = vmin + (j+0.5)*dv  (exact in f32)
  const float vbase = __builtin_fmaf((float)j0 + 0.5f, dv, vmin);

  // ---- moments: n, vbar, e_t (one fused butterfly) ----
  v2 sf = bc(0.f), sfv = bc(0.f), sfv2 = bc(0.f);
  {
    float vt = vbase;
    #pragma unroll
    for (int i = 0; i < 16; ++i) {
      v2 fv = fr[i] * bc(vt);
      sf   += fr[i];
      sfv  += fv;
      sfv2 += fv * bc(vt);
      vt   += dv;
    }
  }
  wred3v(sf, sfv, sfv2);
  v2 vbar = sfv * rcp2(sf);
  v2 nn   = sf * bc(dv);
  v2 e_t  = (sfv2 - vbar * sfv) * bc(dv);
  v2 ret  = rcp2(e_t);
  v2 beta = bc(0.5f) * nn * ret;
  v2 noet = nn * ret;

  // ---- one self-consistent beta iteration (iters 2..10 are f32 no-ops) ----
  {
    v2 karg = beta * bc(-1.44269504f);
    v2 sM = bc(0.f), sMu = bc(0.f);
    float vt = vbase;
    #pragma unroll
    for (int i = 0; i < 16; ++i) {
      v2 d = bc(vt) - vbar;
      v2 q = d * d;
      v2 M = exp2v(karg * q);
      sM  += M;
      sMu += M * q;
      vt  += dv;
    }
    wred2v(sM, sMu);
    beta = beta * (sMu * rcp2(sM)) * noet;
  }

  v2 Dd = bc(0.5f) * rcp2(beta);
  const float idv = rcp1(dv);
  const float s   = dt * nu * idv;
  v2 twobD = (beta + beta) * Dd;         // mirrors reference 2*beta*D
  v2 wfac  = bc(dv) * (beta + beta);     // = dv/D up to rcp rounding
  v2 kA = bc(s) * twobD;                 // Ae = kA*e + cA   (= s*Ce)
  v2 cA = -(kA * vbar);
  v2 kW = twobD * wfac;                  // w  = kW*e + cW
  v2 cW = -(kW * vbar);
  v2 Rv = Dd * bc(s * idv);              // s*De/dv (interior edges)

  // Chang-Cooper delta via Bernoulli series: 1/2 - w/12 + w^3/720 - w^5/30240
  auto edgePQ = [&](float e, v2 &P, v2 &Q) {
    v2 Ae = kA * bc(e) + cA;
    v2 w  = kW * bc(e) + cW;
    v2 w2 = w * w;
    v2 p  = w2 * bc(-3.30687830e-5f) + bc(1.38888889e-3f);
    p     = w2 * p + bc(-8.33333333e-2f);
    v2 dl = w * p + bc(0.5f);
    P = Ae * dl;
    Q = Ae - P;
  };

  // ---- boundary rows 0 and 15 ----
  const float e0pos  = __builtin_fmaf((float)j0, dv, vmin);
  const float e1pos  = e0pos + dv;
  const float e15pos = __builtin_fmaf(15.f, dv, e0pos);
  const float e16pos = e15pos + dv;

  v2 P0, Q0, P1, Q1, P15, Q15, P16, Q16;
  edgePQ(e0pos, P0, Q0);
  edgePQ(e1pos, P1, Q1);
  edgePQ(e15pos, P15, Q15);
  edgePQ(e16pos, P16, Q16);
  v2 R0  = Rv, R16 = Rv;
  if (lane == 0)  { P0  = bc(0.f); Q0  = bc(0.f); R0  = bc(0.f); }
  if (lane == 63) { P16 = bc(0.f); Q16 = bc(0.f); R16 = bc(0.f); }

  v2 a0  = P0 - R0;
  v2 c0  = -(Q1 + Rv);
  v2 b0  = bc(1.f) + (Q0 + R0) + (Rv - P1);
  v2 a15 = P15 - Rv;
  v2 c15 = -(Q16 + R16);
  v2 b15 = bc(1.f) + (Q15 + Rv) + (R16 - P16);

  // ---- interleaved array-free eliminations over interior rows 1..14 ----
  // down state: x_i = Gd + Hd*x_{i-1} + Kd*x15   (processed i = 14 -> 1)
  // up   state: x_i = Gu + Hu*x_{i+1} + Ku*x0    (processed i = 1 -> 14)
  v2 Gu = bc(0.f), Hu = bc(0.f), Ku = bc(1.f);
  v2 Gd = bc(0.f), Hd = bc(0.f), Kd = bc(1.f);
  {
    v2 PuL = P1,  QuL = Q1;    // up cached left edge (edge t)
    v2 PdR = P15, QdR = Q15;   // down cached right edge (edge 16-t)
    float eu = e1pos, ed = e15pos;
    #pragma unroll
    for (int t = 1; t <= 14; ++t) {
      eu += dv;
      v2 PuR, QuR; edgePQ(eu, PuR, QuR);           // edge t+1
      ed -= dv;
      v2 PdL, QdL; edgePQ(ed, PdL, QdL);           // edge 15-t
      // up row t
      v2 au = PuL - Rv;
      v2 cu = -(QuR + Rv);
      v2 bu = bc(1.f) + (QuL + Rv) + (Rv - PuR);
      v2 ru = rcp2(bu + au * Hu);
      Gu = (fr[t] - au * Gu) * ru;
      Hu = -(cu) * ru;
      Ku = -(au * Ku) * ru;
      // down row 15-t
      v2 ad = PdL - Rv;
      v2 cd = -(QdR + Rv);
      v2 bd = bc(1.f) + (QdL + Rv) + (Rv - PdR);
      v2 rd = rcp2(bd + cd * Hd);
      Gd = (fr[15 - t] - cd * Gd) * rd;
      Hd = -(ad) * rd;
      Kd = -(cd * Kd) * rd;
      PuL = PuR; QuL = QuR;
      PdR = PdL; QdR = QdL;
    }
  }
  // now: x1  = Gd + Hd*x0  + Kd*x15
  //      x14 = Gu + Hu*x15 + Ku*x0

  // ---- reduced boundary equations (normalized) ----
  v2 rF = rcp2(b0 + c0 * Hd);
  v2 aA = a0 * rF;                 // couples prev lane's x15
  v2 gA = (c0 * Kd) * rF;          // couples own x15
  v2 dA = (fr[0] - c0 * Gd) * rF;

  v2 rL = rcp2(b15 + a15 * Hu);
  v2 aB = (a15 * Ku) * rL;         // couples own x0
  v2 gB = c15 * rL;                // couples next lane's x0
  v2 dB = (fr[15] - a15 * Gu) * rL;

  // ---- eliminate x15 -> 64-unknown tridiagonal in x0 (one per lane) ----
  v2 aBp = shf(aB, lane - 1);
  v2 gBp = shf(gB, lane - 1);
  v2 dBp = shf(dB, lane - 1);
  // lane 0: aA == 0 exactly (a0 masked), so garbage*0 = 0.
  v2 T  = rcp2(bc(1.f) - aA * gBp - gA * aB);
  v2 pa = -(aA * aBp) * T;
  v2 pg = -(gA * gB) * T;
  v2 pd = (dA - aA * dBp - gA * dB) * T;

  // ---- PCR, 6 steps (exact for 64 unknowns) ----
  #pragma unroll
  for (int st = 1; st <= 32; st <<= 1) {
    v2 La = shf(pa, lane - st), Lg = shf(pg, lane - st), Ld = shf(pd, lane - st);
    v2 Ra = shf(pa, lane + st), Rg = shf(pg, lane + st), Rd = shf(pd, lane + st);
    if (lane < st)      { La = bc(0.f); Lg = bc(0.f); Ld = bc(0.f); }
    if (lane + st > 63) { Ra = bc(0.f); Rg = bc(0.f); Rd = bc(0.f); }
    v2 r   = rcp2(bc(1.f) - pa * Lg - pg * Ra);
    v2 npa = -(pa * La) * r;
    v2 npg = -(pg * Rg) * r;
    v2 npd = (pd - pa * Ld - pg * Rd) * r;
    pa = npa; pg = npg; pd = npd;
  }
  v2 x0v  = pd;
  v2 x0n  = shf(x0v, lane + 1);            // lane 63: gB == 0 kills it
  v2 x15v = dB - aB * x0v - gB * x0n;
  v2 x1v  = Gd + Hd * x0v + Kd * x15v;
  v2 x14v = Gu + Hu * x15v + Ku * x0v;

  // ---- bidirectional reconstruction (meet in the middle) ----
  v2 xu[8], xd[8];
  xu[0] = x0v;  xu[1] = x1v;
  xd[7] = x15v; xd[6] = x14v;
  {
    v2 PrL, QrL, PsR, QsR;
    edgePQ(e1pos, PrL, QrL);     // edge 1
    edgePQ(e15pos, PsR, QsR);    // edge 15
    float eu = e1pos, ed = e15pos;
    #pragma unroll
    for (int i = 1; i <= 6; ++i) {
      // up row i -> x_{i+1}
      eu += dv;
      v2 PrR, QrR; edgePQ(eu, PrR, QrR);           // edge i+1
      v2 ai = PrL - Rv;
      v2 ci = -(QrR + Rv);
      v2 bi = bc(1.f) + (QrL + Rv) + (Rv - PrR);
      xu[i + 1] = (fr[i] - ai * xu[i - 1] - bi * xu[i]) * rcp2(ci);
      PrL = PrR; QrL = QrR;
      // down row j = 15-i -> x_{j-1}
      ed -= dv;
      v2 PsL, QsL; edgePQ(ed, PsL, QsL);           // edge j
      v2 aj = PsL - Rv;
      v2 cj = -(QsR + Rv);
      v2 bj = bc(1.f) + (QsL + Rv) + (Rv - PsR);
      xd[6 - i] = (fr[15 - i] - bj * xd[7 - i] - cj * xd[8 - i]) * rcp2(aj);
      PsR = PsL; QsR = QsL;
    }
  }

  // ---- store both rows ----
  float* o0 = out + (size_t)row0 * NVELL + j0;
  float* o1 = out + (size_t)row1 * NVELL + j0;
  reinterpret_cast<float4*>(o0)[0] = make_float4(xu[0].x, xu[1].x, xu[2].x, xu[3].x);
  reinterpret_cast<float4*>(o1)[0] = make_float4(xu[0].y, xu[1].y, xu[2].y, xu[3].y);
  reinterpret_cast<float4*>(o0)[1] = make_float4(xu[4].x, xu[5].x, xu[6].x, xu[7].x);
  reinterpret_cast<float4*>(o1)[1] = make_float4(xu[4].y, xu[5].y, xu[6].y, xu[7].y);
  reinterpret_cast<float4*>(o0)[2] = make_float4(xd[0].x, xd[1].x, xd[2].x, xd[3].x);
  reinterpret_cast<float4*>(o1)[2] = make_float4(xd[0].y, xd[1].y, xd[2].y, xd[3].y);
  reinterpret_cast<float4*>(o0)[3] = make_float4(xd[4].x, xd[5].x, xd[6].x, xd[7].x);
  reinterpret_cast<float4*>(o1)[3] = make_float4(xd[4].y, xd[5].y, xd[6].y, xd[7].y);
}

extern "C" void kernel_launch(void* const* d_in, const int* in_sizes, int n_in,
                              void* d_out, int out_size, void* d_ws, size_t ws_size,
                              hipStream_t stream) {
  const float* f   = (const float*)d_in[0];
  const float* v   = (const float*)d_in[1];
  const float* ve  = (const float*)d_in[2];
  const float* dvp = (const float*)d_in[3];
  const float* nup = (const float*)d_in[4];
  const float* dtp = (const float*)d_in[5];
  float* out = (float*)d_out;
  int nrows  = in_sizes[0] / NVELL;
  int blocks = (nrows + 7) / 8;
  hipLaunchKernelGGL(fp_step_kernel, dim3(blocks), dim3(256), 0, stream,
                     f, v, ve, dvp, nup, dtp, out, nrows);
}

// Round 5
// 48.941 us; speedup vs baseline: 1.4067x; 1.4067x over previous
//
#include <hip/hip_runtime.h>

#define NVELL 1024

typedef float v2 __attribute__((ext_vector_type(2)));

__device__ __forceinline__ float rcp1(float x){ return __builtin_amdgcn_rcpf(x); }
__device__ __forceinline__ v2 bc(float x){ v2 r = {x, x}; return r; }
__device__ __forceinline__ v2 rcp2(v2 x){ v2 r = {rcp1(x.x), rcp1(x.y)}; return r; }
__device__ __forceinline__ v2 exp2v(v2 x){ v2 r = {exp2f(x.x), exp2f(x.y)}; return r; }
__device__ __forceinline__ v2 shf(v2 x, int src){
  v2 r = {__shfl(x.x, src, 64), __shfl(x.y, src, 64)}; return r;
}

__device__ __forceinline__ void wred3v(v2 &a, v2 &b, v2 &c) {
  #pragma unroll
  for (int off = 1; off < 64; off <<= 1) {
    a.x += __shfl_xor(a.x, off, 64); a.y += __shfl_xor(a.y, off, 64);
    b.x += __shfl_xor(b.x, off, 64); b.y += __shfl_xor(b.y, off, 64);
    c.x += __shfl_xor(c.x, off, 64); c.y += __shfl_xor(c.y, off, 64);
  }
}
__device__ __forceinline__ void wred2v(v2 &a, v2 &b) {
  #pragma unroll
  for (int off = 1; off < 64; off <<= 1) {
    a.x += __shfl_xor(a.x, off, 64); a.y += __shfl_xor(a.y, off, 64);
    b.x += __shfl_xor(b.x, off, 64); b.y += __shfl_xor(b.y, off, 64);
  }
}

__global__ __launch_bounds__(256, 3) void fp_step_kernel(
    const float* __restrict__ f, const float* __restrict__ v,
    const float* __restrict__ ve, const float* __restrict__ p_dv,
    const float* __restrict__ p_nu, const float* __restrict__ p_dt,
    float* __restrict__ out, int nrows)
{
  const int lane = threadIdx.x & 63;
  const int wid  = threadIdx.x >> 6;
  const int row0 = blockIdx.x * 8 + wid * 2;
  if (row0 >= nrows) return;
  const int row1 = (row0 + 1 < nrows) ? (row0 + 1) : row0;

  const float dv   = *p_dv;
  const float nu   = *p_nu;
  const float dt   = *p_dt;
  const float vmin = ve[0];
  const int   j0   = lane * 16;

  // ---- load f for both rows (16 contiguous elements per lane, packed) ----
  const float* f0p = f + (size_t)row0 * NVELL + j0;
  const float* f1p = f + (size_t)row1 * NVELL + j0;
  v2 fr[16];
  #pragma unroll
  for (int k = 0; k < 4; ++k) {
    float4 a = reinterpret_cast<const float4*>(f0p)[k];
    float4 b = reinterpret_cast<const float4*>(f1p)[k];
    fr[4*k+0] = (v2){a.x, b.x};
    fr[4*k+1] = (v2){a.y, b.y};
    fr[4*k+2] = (v2){a.z, b.z};
    fr[4*k+3] = (v2){a.w, b.w};
  }

  // cell centers: v_j = vmin + (j+0.5)*dv  (exact in f32)
  const float vbase = __builtin_fmaf((float)j0 + 0.5f, dv, vmin);

  // ---- moments: n, vbar, e_t (one fused butterfly) ----
  v2 sf = bc(0.f), sfv = bc(0.f), sfv2 = bc(0.f);
  {
    float vt = vbase;
    #pragma unroll
    for (int i = 0; i < 16; ++i) {
      v2 fv = fr[i] * bc(vt);
      sf   += fr[i];
      sfv  += fv;
      sfv2 += fv * bc(vt);
      vt   += dv;
    }
  }
  wred3v(sf, sfv, sfv2);
  v2 vbar = sfv * rcp2(sf);
  v2 nn   = sf * bc(dv);
  v2 e_t  = (sfv2 - vbar * sfv) * bc(dv);
  v2 ret  = rcp2(e_t);
  v2 beta = bc(0.5f) * nn * ret;
  v2 noet = nn * ret;

  // ---- one self-consistent beta iteration (iters 2..10 are f32 no-ops) ----
  {
    v2 karg = beta * bc(-1.44269504f);
    v2 sM = bc(0.f), sMu = bc(0.f);
    float vt = vbase;
    #pragma unroll
    for (int i = 0; i < 16; ++i) {
      v2 d = bc(vt) - vbar;
      v2 q = d * d;
      v2 M = exp2v(karg * q);
      sM  += M;
      sMu += M * q;
      vt  += dv;
    }
    wred2v(sM, sMu);
    beta = beta * (sMu * rcp2(sM)) * noet;
  }

  v2 Dd = bc(0.5f) * rcp2(beta);
  const float idv = rcp1(dv);
  const float s   = dt * nu * idv;
  v2 twobD = (beta + beta) * Dd;         // mirrors reference 2*beta*D
  v2 wfac  = bc(dv) * (beta + beta);     // = dv/D up to rcp rounding
  v2 kA = bc(s) * twobD;                 // Ae = kA*e + cA   (= s*Ce)
  v2 cA = -(kA * vbar);
  v2 kW = twobD * wfac;                  // w  = kW*e + cW
  v2 cW = -(kW * vbar);
  v2 Rv = Dd * bc(s * idv);              // s*De/dv (interior edges)

  // Chang-Cooper delta via Bernoulli series: 1/2 - w/12 + w^3/720 - w^5/30240
  auto edgePQ = [&](float e, v2 &P, v2 &Q) {
    v2 Ae = kA * bc(e) + cA;
    v2 w  = kW * bc(e) + cW;
    v2 w2 = w * w;
    v2 p  = w2 * bc(-3.30687830e-5f) + bc(1.38888889e-3f);
    p     = w2 * p + bc(-8.33333333e-2f);
    v2 dl = w * p + bc(0.5f);
    P = Ae * dl;
    Q = Ae - P;
  };

  // ---- boundary rows 0 and 15 ----
  const float e0pos  = __builtin_fmaf((float)j0, dv, vmin);
  const float e1pos  = e0pos + dv;
  const float e15pos = __builtin_fmaf(15.f, dv, e0pos);
  const float e16pos = e15pos + dv;

  v2 P0, Q0, P1, Q1, P15, Q15, P16, Q16;
  edgePQ(e0pos, P0, Q0);
  edgePQ(e1pos, P1, Q1);
  edgePQ(e15pos, P15, Q15);
  edgePQ(e16pos, P16, Q16);
  v2 R0  = Rv, R16 = Rv;
  if (lane == 0)  { P0  = bc(0.f); Q0  = bc(0.f); R0  = bc(0.f); }
  if (lane == 63) { P16 = bc(0.f); Q16 = bc(0.f); R16 = bc(0.f); }

  v2 a0  = P0 - R0;
  v2 c0  = -(Q1 + Rv);
  v2 b0  = bc(1.f) + (Q0 + R0) + (Rv - P1);
  v2 a15 = P15 - Rv;
  v2 c15 = -(Q16 + R16);
  v2 b15 = bc(1.f) + (Q15 + Rv) + (R16 - P16);

  // ---- interleaved array-free eliminations over interior rows 1..14 ----
  // down state: x_i = Gd + Hd*x_{i-1} + Kd*x15   (processed i = 14 -> 1)
  // up   state: x_i = Gu + Hu*x_{i+1} + Ku*x0    (processed i = 1 -> 14)
  v2 Gu = bc(0.f), Hu = bc(0.f), Ku = bc(1.f);
  v2 Gd = bc(0.f), Hd = bc(0.f), Kd = bc(1.f);
  {
    v2 PuL = P1,  QuL = Q1;    // up cached left edge (edge t)
    v2 PdR = P15, QdR = Q15;   // down cached right edge (edge 16-t)
    float eu = e1pos, ed = e15pos;
    #pragma unroll
    for (int t = 1; t <= 14; ++t) {
      eu += dv;
      v2 PuR, QuR; edgePQ(eu, PuR, QuR);           // edge t+1
      ed -= dv;
      v2 PdL, QdL; edgePQ(ed, PdL, QdL);           // edge 15-t
      // up row t
      v2 au = PuL - Rv;
      v2 cu = -(QuR + Rv);
      v2 bu = bc(1.f) + (QuL + Rv) + (Rv - PuR);
      v2 ru = rcp2(bu + au * Hu);
      Gu = (fr[t] - au * Gu) * ru;
      Hu = -(cu) * ru;
      Ku = -(au * Ku) * ru;
      // down row 15-t
      v2 ad = PdL - Rv;
      v2 cd = -(QdR + Rv);
      v2 bd = bc(1.f) + (QdL + Rv) + (Rv - PdR);
      v2 rd = rcp2(bd + cd * Hd);
      Gd = (fr[15 - t] - cd * Gd) * rd;
      Hd = -(ad) * rd;
      Kd = -(cd * Kd) * rd;
      PuL = PuR; QuL = QuR;
      PdR = PdL; QdR = QdL;
    }
  }
  // now: x1  = Gd + Hd*x0  + Kd*x15
  //      x14 = Gu + Hu*x15 + Ku*x0

  // ---- reduced boundary equations (normalized) ----
  v2 rF = rcp2(b0 + c0 * Hd);
  v2 aA = a0 * rF;                 // couples prev lane's x15
  v2 gA = (c0 * Kd) * rF;          // couples own x15
  v2 dA = (fr[0] - c0 * Gd) * rF;

  v2 rL = rcp2(b15 + a15 * Hu);
  v2 aB = (a15 * Ku) * rL;         // couples own x0
  v2 gB = c15 * rL;                // couples next lane's x0
  v2 dB = (fr[15] - a15 * Gu) * rL;

  // ---- eliminate x15 -> 64-unknown tridiagonal in x0 (one per lane) ----
  v2 aBp = shf(aB, lane - 1);
  v2 gBp = shf(gB, lane - 1);
  v2 dBp = shf(dB, lane - 1);
  // lane 0: aA == 0 exactly (a0 masked), so garbage*0 = 0.
  v2 T  = rcp2(bc(1.f) - aA * gBp - gA * aB);
  v2 pa = -(aA * aBp) * T;
  v2 pg = -(gA * gB) * T;
  v2 pd = (dA - aA * dBp - gA * dB) * T;

  // ---- PCR, 6 steps (exact for 64 unknowns) ----
  #pragma unroll
  for (int st = 1; st <= 32; st <<= 1) {
    v2 La = shf(pa, lane - st), Lg = shf(pg, lane - st), Ld = shf(pd, lane - st);
    v2 Ra = shf(pa, lane + st), Rg = shf(pg, lane + st), Rd = shf(pd, lane + st);
    if (lane < st)      { La = bc(0.f); Lg = bc(0.f); Ld = bc(0.f); }
    if (lane + st > 63) { Ra = bc(0.f); Rg = bc(0.f); Rd = bc(0.f); }
    v2 r   = rcp2(bc(1.f) - pa * Lg - pg * Ra);
    v2 npa = -(pa * La) * r;
    v2 npg = -(pg * Rg) * r;
    v2 npd = (pd - pa * Ld - pg * Rd) * r;
    pa = npa; pg = npg; pd = npd;
  }
  v2 x0v  = pd;
  v2 x0n  = shf(x0v, lane + 1);            // lane 63: gB == 0 kills it
  v2 x15v = dB - aB * x0v - gB * x0n;
  v2 x1v  = Gd + Hd * x0v + Kd * x15v;
  v2 x14v = Gu + Hu * x15v + Ku * x0v;

  // ---- bidirectional reconstruction (meet in the middle) ----
  v2 xu[8], xd[8];
  xu[0] = x0v;  xu[1] = x1v;
  xd[7] = x15v; xd[6] = x14v;
  {
    v2 PrL, QrL, PsR, QsR;
    edgePQ(e1pos, PrL, QrL);     // edge 1
    edgePQ(e15pos, PsR, QsR);    // edge 15
    float eu = e1pos, ed = e15pos;
    #pragma unroll
    for (int i = 1; i <= 6; ++i) {
      // up row i -> x_{i+1}
      eu += dv;
      v2 PrR, QrR; edgePQ(eu, PrR, QrR);           // edge i+1
      v2 ai = PrL - Rv;
      v2 ci = -(QrR + Rv);
      v2 bi = bc(1.f) + (QrL + Rv) + (Rv - PrR);
      xu[i + 1] = (fr[i] - ai * xu[i - 1] - bi * xu[i]) * rcp2(ci);
      PrL = PrR; QrL = QrR;
      // down row j = 15-i -> x_{j-1}
      ed -= dv;
      v2 PsL, QsL; edgePQ(ed, PsL, QsL);           // edge j
      v2 aj = PsL - Rv;
      v2 cj = -(QsR + Rv);
      v2 bj = bc(1.f) + (QsL + Rv) + (Rv - PsR);
      xd[6 - i] = (fr[15 - i] - bj * xd[7 - i] - cj * xd[8 - i]) * rcp2(aj);
      PsR = PsL; QsR = QsL;
    }
  }

  // ---- store both rows ----
  float* o0 = out + (size_t)row0 * NVELL + j0;
  float* o1 = out + (size_t)row1 * NVELL + j0;
  reinterpret_cast<float4*>(o0)[0] = make_float4(xu[0].x, xu[1].x, xu[2].x, xu[3].x);
  reinterpret_cast<float4*>(o1)[0] = make_float4(xu[0].y, xu[1].y, xu[2].y, xu[3].y);
  reinterpret_cast<float4*>(o0)[1] = make_float4(xu[4].x, xu[5].x, xu[6].x, xu[7].x);
  reinterpret_cast<float4*>(o1)[1] = make_float4(xu[4].y, xu[5].y, xu[6].y, xu[7].y);
  reinterpret_cast<float4*>(o0)[2] = make_float4(xd[0].x, xd[1].x, xd[2].x, xd[3].x);
  reinterpret_cast<float4*>(o1)[2] = make_float4(xd[0].y, xd[1].y, xd[2].y, xd[3].y);
  reinterpret_cast<float4*>(o0)[3] = make_float4(xd[4].x, xd[5].x, xd[6].x, xd[7].x);
  reinterpret_cast<float4*>(o1)[3] = make_float4(xd[4].y, xd[5].y, xd[6].y, xd[7].y);
}

extern "C" void kernel_launch(void* const* d_in, const int* in_sizes, int n_in,
                              void* d_out, int out_size, void* d_ws, size_t ws_size,
                              hipStream_t stream) {
  const float* f   = (const float*)d_in[0];
  const float* v   = (const float*)d_in[1];
  const float* ve  = (const float*)d_in[2];
  const float* dvp = (const float*)d_in[3];
  const float* nup = (const float*)d_in[4];
  const float* dtp = (const float*)d_in[5];
  float* out = (float*)d_out;
  int nrows  = in_sizes[0] / NVELL;
  int blocks = (nrows + 7) / 8;
  hipLaunchKernelGGL(fp_step_kernel, dim3(blocks), dim3(256), 0, stream,
                     f, v, ve, dvp, nup, dtp, out, nrows);
}